// Round 3
// baseline (39900.339 us; speedup 1.0000x reference)
//
#include <hip/hip_runtime.h>
#include <hip/hip_bf16.h>
#include <math.h>

// ---------------------------------------------------------------------------
// RGN model: T=700 B=32 H=800 EMB=32 EVO=21 A=60
// External dtypes: float32 in / float32 out (per reference). Internal: bf16
// MFMA. Pipeline: cvt/pack weights -> xpad -> persistent biLSTM x2 (MFMA +
// global barrier per step) -> FC/softmax/dihedral (MFMA) -> sequential NeRF.
// Workspace ~189 MiB.
// ---------------------------------------------------------------------------

typedef unsigned int u32;
typedef __bf16 bf16x8 __attribute__((ext_vector_type(8)));
typedef float  f32x4  __attribute__((ext_vector_type(4)));

#define TT 700
#define BT 32
#define HROW 1600
#define ASTRIDE 872        // LDS A stride (bf16 elems): 16B aligned
#define NWG 100

__device__ __forceinline__ f32x4 mfma16(bf16x8 a, bf16x8 b, f32x4 c) {
  return __builtin_amdgcn_mfma_f32_16x16x32_bf16(a, b, c, 0, 0, 0);
}
__device__ __forceinline__ float sigf(float x) { return 1.f / (1.f + __expf(-x)); }

// ---------------- pack / init kernels ----------------
__global__ void cvt_f32_bf16_kernel(const float* __restrict__ src,
                                    __bf16* __restrict__ dst, int n) {
  for (int i = blockIdx.x * 256 + threadIdx.x; i < n; i += gridDim.x * 256)
    dst[i] = (__bf16)src[i];
}

__global__ void pack_wx0_kernel(const float* Wih0f, const float* Wih0b, __bf16* wx0) {
  int idx = blockIdx.x * 256 + threadIdx.x;      // 2*3200*64 = 409600 exact
  if (idx >= 2 * 3200 * 64) return;
  int d = idx / (3200 * 64);
  int r = (idx / 64) % 3200;
  int k = idx % 64;
  const float* W = d ? Wih0b : Wih0f;
  wx0[idx] = (k < 53) ? (__bf16)W[(size_t)r * 53 + k] : (__bf16)0.f;
}

__global__ void pack_fc_kernel(const float* fcW, __bf16* wfc) {
  int idx = blockIdx.x * 256 + threadIdx.x;
  if (idx >= 64 * 1664) return;
  int a = idx / 1664, k = idx % 1664;
  __bf16 v = (__bf16)0.f;
  if (a < 60 && k < 1653) v = (__bf16)fcW[(size_t)a * 1653 + k];
  wfc[idx] = v;
}

__global__ void xpad_kernel(const int* primary, const float* evo,
                            const float* emb, __bf16* xpad) {
  int idx = blockIdx.x * 256 + threadIdx.x;   // 700*32*64 exact
  int t = idx >> 11;
  int b = (idx >> 6) & 31;
  int k = idx & 63;
  __bf16 v = (__bf16)0.f;
  if (k < 32)      v = (__bf16)emb[primary[t * 32 + b] * 32 + k];
  else if (k < 53) v = (__bf16)evo[((size_t)t * 32 + b) * 21 + (k - 32)];
  xpad[idx] = v;
}

__global__ void small_init_kernel(__bf16* zerobuf, u32* counter,
                                  float* sinA, float* cosA, const float* alpha) {
  int idx = blockIdx.x * 256 + threadIdx.x;
  if (idx < 32 * 1600) zerobuf[idx] = (__bf16)0.f;
  int j = idx - 32 * 1600;
  if (j >= 0 && j < 192) {
    if (j < 180) {
      float v = alpha[j];
      sinA[j] = sinf(v);
      cosA[j] = cosf(v);
    } else { sinA[j] = 0.f; cosA[j] = 0.f; }
  }
  if (j == 192) *counter = 0u;
}

// ---------------- persistent biLSTM ----------------
struct LstmArgs {
  const __bf16 *xpad, *wx0, *zero;
  const __bf16 *wh0, *wh1, *wi1;     // packed bf16: [dir][3200][800/800/1600]
  __bf16 *h0, *h1;
  const float *b0f, *b0b, *b1f, *b1b;
  u32* counter;
};

__device__ __forceinline__ void gbar(u32* cnt, unsigned& gen) {
  __syncthreads();
  __threadfence();   // release (agent scope: L2 writeback on gfx950)
  ++gen;
  if (threadIdx.x == 0) {
    __hip_atomic_fetch_add(cnt, 1u, __ATOMIC_RELEASE, __HIP_MEMORY_SCOPE_AGENT);
    const unsigned tgt = gen * (unsigned)NWG;
    while (__hip_atomic_load(cnt, __ATOMIC_ACQUIRE, __HIP_MEMORY_SCOPE_AGENT) < tgt)
      __builtin_amdgcn_s_sleep(2);
  }
  __syncthreads();
  __threadfence();   // acquire (agent scope: cache invalidate)
}

template <int LAYER>
__device__ __forceinline__ void run_layer(
    const __bf16* __restrict__ Whh,   // (3200,800) bf16, dir-selected
    const __bf16* __restrict__ Wx,    // L0: wx0+d*3200*64 (rows of 64); L1: wi1 dir (3200,1600)
    const float*  __restrict__ bias,
    const __bf16* __restrict__ aux,   // L0: xpad [t][b][64]; L1: h0 [t][b][1600]
    const __bf16* __restrict__ hself, // own-layer h output (prev-step source)
    __bf16* __restrict__ hdst,
    const __bf16* __restrict__ zerobuf,
    u32* counter, unsigned& gen, int d, int u0,
    __bf16* u_lds, float* g_lds) {
  constexpr int NPASS = LAYER ? 3 : 1;
  constexpr int NGRP  = LAYER ? 100 : 108; // 8-elem staging groups per row

  const int tid  = threadIdx.x;
  const int wave = tid >> 6;
  const int lane = tid & 63;
  const int nidx = lane & 15;
  const int q    = lane >> 4;
  const int dcol = d * 800;
  const int row  = wave * 800 + u0 + nidx;          // gate row in [0,3200)
  const float bias_n = bias[row];
  const __bf16* whh_row = Whh + (size_t)row * 800 + q * 8;
  const __bf16* wx_row  = LAYER ? (Wx + (size_t)row * 1600 + q * 8)
                                : (Wx + (size_t)row * 64 + q * 8);
  const int bb = tid >> 3, g0 = tid & 7;
  const int pb0 = tid >> 4, pu = tid & 15, pb1 = 16 + (tid >> 4);
  float c0 = 0.f, c1 = 0.f;

#pragma unroll 1
  for (int s = 0; s < TT; ++s) {
    const int tt = d ? (TT - 1 - s) : s;
    const __bf16* hprev =
        (s == 0) ? zerobuf
                 : (hself + (size_t)(d ? tt + 1 : tt - 1) * (BT * HROW));
    f32x4 acc0 = {0.f, 0.f, 0.f, 0.f}, acc1 = {0.f, 0.f, 0.f, 0.f};

#pragma unroll
    for (int pass = 0; pass < NPASS; ++pass) {
      // ---- stage u chunk into LDS (coalesced 16B groups) ----
      for (int g = g0; g < NGRP; g += 8) {
        const int kk = g * 8;
        bf16x8 v;
        if (LAYER == 0) {
          if (kk < 800)
            v = *(const bf16x8*)(hprev + (size_t)bb * HROW + dcol + kk);
          else
            v = *(const bf16x8*)(aux + ((size_t)tt * BT + bb) * 64 + (kk - 800));
        } else {
          if (pass == 0)
            v = *(const bf16x8*)(hprev + (size_t)bb * HROW + dcol + kk);
          else
            v = *(const bf16x8*)(aux + ((size_t)tt * BT + bb) * HROW +
                                 (pass - 1) * 800 + kk);
        }
        *(bf16x8*)(u_lds + bb * ASTRIDE + kk) = v;
      }
      __syncthreads();

      if (LAYER == 0) {
#pragma unroll
        for (int sl = 0; sl < 25; ++sl) {       // k in [0,800): Whh
          bf16x8 bfr = *(const bf16x8*)(whh_row + sl * 32);
          bf16x8 a0 = *(const bf16x8*)(u_lds + nidx * ASTRIDE + sl * 32 + q * 8);
          bf16x8 a1 = *(const bf16x8*)(u_lds + (16 + nidx) * ASTRIDE + sl * 32 + q * 8);
          acc0 = mfma16(a0, bfr, acc0);
          acc1 = mfma16(a1, bfr, acc1);
        }
#pragma unroll
        for (int sl = 25; sl < 27; ++sl) {      // k in [800,864): packed x-part
          bf16x8 bfr = *(const bf16x8*)(wx_row + (sl - 25) * 32);
          bf16x8 a0 = *(const bf16x8*)(u_lds + nidx * ASTRIDE + sl * 32 + q * 8);
          bf16x8 a1 = *(const bf16x8*)(u_lds + (16 + nidx) * ASTRIDE + sl * 32 + q * 8);
          acc0 = mfma16(a0, bfr, acc0);
          acc1 = mfma16(a1, bfr, acc1);
        }
      } else {
        const __bf16* wr = (pass == 0) ? whh_row : (wx_row + (pass - 1) * 800);
#pragma unroll
        for (int sl = 0; sl < 25; ++sl) {
          bf16x8 bfr = *(const bf16x8*)(wr + sl * 32);
          bf16x8 a0 = *(const bf16x8*)(u_lds + nidx * ASTRIDE + sl * 32 + q * 8);
          bf16x8 a1 = *(const bf16x8*)(u_lds + (16 + nidx) * ASTRIDE + sl * 32 + q * 8);
          acc0 = mfma16(a0, bfr, acc0);
          acc1 = mfma16(a1, bfr, acc1);
        }
      }
      __syncthreads();
    }

    // ---- gate exchange (C layout: col=lane&15=unit, row=q*4+r=batch) ----
#pragma unroll
    for (int r = 0; r < 4; ++r) {
      g_lds[wave * 512 + (q * 4 + r) * 16 + nidx]      = acc0[r] + bias_n;
      g_lds[wave * 512 + (16 + q * 4 + r) * 16 + nidx] = acc1[r] + bias_n;
    }
    __syncthreads();

    // ---- nonlinearity: thread owns (b=pb0,u) and (b=pb1,u) ----
    {
      float i0 = g_lds[0 * 512 + pb0 * 16 + pu], f0 = g_lds[1 * 512 + pb0 * 16 + pu];
      float gg0 = g_lds[2 * 512 + pb0 * 16 + pu], o0 = g_lds[3 * 512 + pb0 * 16 + pu];
      c0 = sigf(f0) * c0 + sigf(i0) * tanhf(gg0);
      hdst[((size_t)tt * BT + pb0) * HROW + dcol + u0 + pu] =
          (__bf16)(sigf(o0) * tanhf(c0));
      float i1 = g_lds[0 * 512 + pb1 * 16 + pu], f1 = g_lds[1 * 512 + pb1 * 16 + pu];
      float gg1 = g_lds[2 * 512 + pb1 * 16 + pu], o1 = g_lds[3 * 512 + pb1 * 16 + pu];
      c1 = sigf(f1) * c1 + sigf(i1) * tanhf(gg1);
      hdst[((size_t)tt * BT + pb1) * HROW + dcol + u0 + pu] =
          (__bf16)(sigf(o1) * tanhf(c1));
    }
    gbar(counter, gen);
  }
}

__global__ __launch_bounds__(256, 1) void lstm_kernel(LstmArgs A) {
  __shared__ __align__(16) __bf16 u_lds[32 * ASTRIDE];  // 55,808 B
  __shared__ float g_lds[4 * 32 * 16];                  // 8,192 B
  const int wg = blockIdx.x;
  const int d  = wg / 50;
  const int u0 = (wg % 50) * 16;
  unsigned gen = 0;
  run_layer<0>(A.wh0 + (size_t)d * 3200 * 800, A.wx0 + (size_t)d * 3200 * 64,
               d ? A.b0b : A.b0f, A.xpad, A.h0, A.h0, A.zero,
               A.counter, gen, d, u0, u_lds, g_lds);
  run_layer<1>(A.wh1 + (size_t)d * 3200 * 800, A.wi1 + (size_t)d * 3200 * 1600,
               d ? A.b1b : A.b1f, A.h0, A.h1, A.h1, A.zero,
               A.counter, gen, d, u0, u_lds, g_lds);
}

// ---------------- FC + softmax + dihedral -> points ----------------
__global__ __launch_bounds__(256) void fc_kernel(
    const __bf16* __restrict__ h1, const __bf16* __restrict__ xpad,
    const __bf16* __restrict__ wfc, const float* __restrict__ fcb,
    const float* __restrict__ sinA, const float* __restrict__ cosA,
    float* __restrict__ pts) {
  __shared__ float lg[32 * 64];
  const int t = blockIdx.x, tid = threadIdx.x;
  const int wave = tid >> 6, lane = tid & 63, nidx = lane & 15, q = lane >> 4;
  const int a_col = wave * 16 + nidx;
  const __bf16* wrow = wfc + (size_t)a_col * 1664 + q * 8;
  const __bf16* h1row = h1 + (size_t)t * BT * HROW;
  const __bf16* xrow  = xpad + (size_t)t * BT * 64;
  f32x4 acc0 = {0.f, 0.f, 0.f, 0.f}, acc1 = {0.f, 0.f, 0.f, 0.f};
#pragma unroll
  for (int sl = 0; sl < 52; ++sl) {
    const int k = sl * 32 + q * 8;
    bf16x8 a0, a1;
    if (sl < 50) {
      a0 = *(const bf16x8*)(h1row + (size_t)nidx * HROW + k);
      a1 = *(const bf16x8*)(h1row + (size_t)(16 + nidx) * HROW + k);
    } else {
      a0 = *(const bf16x8*)(xrow + nidx * 64 + (k - 1600));
      a1 = *(const bf16x8*)(xrow + (16 + nidx) * 64 + (k - 1600));
    }
    bf16x8 bfr = *(const bf16x8*)(wrow + sl * 32);
    acc0 = mfma16(a0, bfr, acc0);
    acc1 = mfma16(a1, bfr, acc1);
  }
  const float bn = (a_col < 60) ? fcb[a_col] : -1e30f;
#pragma unroll
  for (int r = 0; r < 4; ++r) {
    lg[(q * 4 + r) * 64 + a_col]      = acc0[r] + bn;
    lg[(16 + q * 4 + r) * 64 + a_col] = acc1[r] + bn;
  }
  __syncthreads();

  // softmax over 60 + dihedral; 8 threads per batch row
  const int b = tid >> 3, j = tid & 7;
  float v[8];
  float m = -1e30f;
#pragma unroll
  for (int k2 = 0; k2 < 8; ++k2) {
    v[k2] = lg[b * 64 + j + 8 * k2];
    m = fmaxf(m, v[k2]);
  }
  m = fmaxf(m, __shfl_xor(m, 1, 8));
  m = fmaxf(m, __shfl_xor(m, 2, 8));
  m = fmaxf(m, __shfl_xor(m, 4, 8));
  float s = 0.f;
#pragma unroll
  for (int k2 = 0; k2 < 8; ++k2) { v[k2] = __expf(v[k2] - m); s += v[k2]; }
  s += __shfl_xor(s, 1, 8);
  s += __shfl_xor(s, 2, 8);
  s += __shfl_xor(s, 4, 8);
  const float inv = 1.f / s;
  float ps[3] = {0.f, 0.f, 0.f}, pc[3] = {0.f, 0.f, 0.f};
#pragma unroll
  for (int k2 = 0; k2 < 8; ++k2) {
    const int a = j + 8 * k2;
    const float p = v[k2] * inv;
#pragma unroll
    for (int c = 0; c < 3; ++c) {
      ps[c] += p * sinA[a * 3 + c];
      pc[c] += p * cosA[a * 3 + c];
    }
  }
#pragma unroll
  for (int c = 0; c < 3; ++c) {
    ps[c] += __shfl_xor(ps[c], 1, 8);
    ps[c] += __shfl_xor(ps[c], 2, 8);
    ps[c] += __shfl_xor(ps[c], 4, 8);
    pc[c] += __shfl_xor(pc[c], 1, 8);
    pc[c] += __shfl_xor(pc[c], 2, 8);
    pc[c] += __shfl_xor(pc[c], 4, 8);
  }
  if (j == 0) {
    const float BL[3] = {145.801f, 152.326f, 132.868f};
    const float BA[3] = {2.124f, 1.941f, 2.028f};
#pragma unroll
    for (int c = 0; c < 3; ++c) {
      const float ang = 3.14159265358979323846f - BA[c];
      const float rct = BL[c] * cosf(ang), rst = BL[c] * sinf(ang);
      const float dih = atan2f(ps[c], pc[c]);
      float* o = pts + ((size_t)(3 * t + c) * BT + b) * 3;
      o[0] = rct;
      o[1] = cosf(dih) * rst;
      o[2] = sinf(dih) * rst;
    }
  }
}

// ---------------- sequential NeRF extension ----------------
__global__ void nerf_kernel(const float* __restrict__ pts, float* __restrict__ out) {
  const int b = threadIdx.x;
  if (b >= 32) return;
  float ax = -0.70710678f, ay = 1.22474487f, az = 0.f;
  float bx = -1.41421356f, by = 0.f, bz = 0.f;
  float cx = 0.f, cy = 0.f, cz = 0.f;
#pragma unroll 4
  for (int i = 0; i < 3 * TT; ++i) {
    const float* p = pts + ((size_t)i * BT + b) * 3;
    const float p0 = p[0], p1 = p[1], p2 = p[2];
    float ux = cx - bx, uy = cy - by, uz = cz - bz;
    const float ri = rsqrtf(ux * ux + uy * uy + uz * uz + 1e-12f);
    ux *= ri; uy *= ri; uz *= ri;
    const float wx = bx - ax, wy = by - ay, wz = bz - az;
    float nx = wy * uz - wz * uy, ny = wz * ux - wx * uz, nz = wx * uy - wy * ux;
    const float rn = rsqrtf(nx * nx + ny * ny + nz * nz + 1e-12f);
    nx *= rn; ny *= rn; nz *= rn;
    const float mx = ny * uz - nz * uy, my = nz * ux - nx * uz, mz = nx * uy - ny * ux;
    const float ox = cx + p0 * ux + p1 * mx + p2 * nx;
    const float oy = cy + p0 * uy + p1 * my + p2 * ny;
    const float oz = cz + p0 * uz + p1 * mz + p2 * nz;
    out[((size_t)i * BT + b) * 3 + 0] = ox;
    out[((size_t)i * BT + b) * 3 + 1] = oy;
    out[((size_t)i * BT + b) * 3 + 2] = oz;
    ax = bx; ay = by; az = bz;
    bx = cx; by = cy; bz = cz;
    cx = ox; cy = oy; cz = oz;
  }
}

// ---------------- launch ----------------
extern "C" void kernel_launch(void* const* d_in, const int* in_sizes, int n_in,
                              void* d_out, int out_size, void* d_ws, size_t ws_size,
                              hipStream_t stream) {
  (void)in_sizes; (void)n_in; (void)out_size;
  const int*   primary = (const int*)d_in[0];
  const float* evo     = (const float*)d_in[1];
  const float* emb     = (const float*)d_in[3];
  const float* Wih0f   = (const float*)d_in[4];
  const float* Whh0f   = (const float*)d_in[5];
  const float* b0f     = (const float*)d_in[6];
  const float* Wih0b   = (const float*)d_in[7];
  const float* Whh0b   = (const float*)d_in[8];
  const float* b0b     = (const float*)d_in[9];
  const float* Wih1f   = (const float*)d_in[10];
  const float* Whh1f   = (const float*)d_in[11];
  const float* b1f     = (const float*)d_in[12];
  const float* Wih1b   = (const float*)d_in[13];
  const float* Whh1b   = (const float*)d_in[14];
  const float* b1b     = (const float*)d_in[15];
  const float* fcW     = (const float*)d_in[16];
  const float* fcb     = (const float*)d_in[17];
  const float* alpha   = (const float*)d_in[18];

  char* ws = (char*)d_ws;
  size_t off = 0;
  auto take = [&](size_t n) -> void* {
    void* p = ws + off;
    off += (n + 511) & ~(size_t)511;
    return p;
  };
  __bf16* xpad = (__bf16*)take((size_t)TT * BT * 64 * 2);      // 2.87 MB
  __bf16* zb   = (__bf16*)take((size_t)BT * HROW * 2);         // 102 KB
  __bf16* wx0  = (__bf16*)take((size_t)2 * 3200 * 64 * 2);     // 819 KB
  __bf16* wfc  = (__bf16*)take((size_t)64 * 1664 * 2);         // 213 KB
  float*  sinA = (float*)take(192 * 4);
  float*  cosA = (float*)take(192 * 4);
  float*  pts  = (float*)take((size_t)3 * TT * BT * 3 * 4);    // 806 KB
  u32*    cnt  = (u32*)take(512);
  __bf16* wh0  = (__bf16*)take((size_t)2 * 3200 * 800 * 2);    // 10.24 MB
  __bf16* wh1  = (__bf16*)take((size_t)2 * 3200 * 800 * 2);    // 10.24 MB
  __bf16* wi1  = (__bf16*)take((size_t)2 * 3200 * 1600 * 2);   // 20.48 MB
  __bf16* h0   = (__bf16*)take((size_t)TT * BT * HROW * 2);    // 71.68 MB
  __bf16* h1   = (__bf16*)take((size_t)TT * BT * HROW * 2);    // 71.68 MB
  if (off > ws_size) return;  // failure signature: absmax == max|ref| == 233472

  const int NW = 3200 * 800;   // 2.56M elems per direction (Whh)
  const int NI = 3200 * 1600;  // 5.12M elems per direction (Wih1)
  cvt_f32_bf16_kernel<<<2048, 256, 0, stream>>>(Whh0f, wh0, NW);
  cvt_f32_bf16_kernel<<<2048, 256, 0, stream>>>(Whh0b, wh0 + NW, NW);
  cvt_f32_bf16_kernel<<<2048, 256, 0, stream>>>(Whh1f, wh1, NW);
  cvt_f32_bf16_kernel<<<2048, 256, 0, stream>>>(Whh1b, wh1 + NW, NW);
  cvt_f32_bf16_kernel<<<2048, 256, 0, stream>>>(Wih1f, wi1, NI);
  cvt_f32_bf16_kernel<<<2048, 256, 0, stream>>>(Wih1b, wi1 + NI, NI);
  pack_wx0_kernel<<<1600, 256, 0, stream>>>(Wih0f, Wih0b, wx0);
  pack_fc_kernel<<<(64 * 1664 + 255) / 256, 256, 0, stream>>>(fcW, wfc);
  xpad_kernel<<<(TT * BT * 64) / 256, 256, 0, stream>>>(primary, evo, emb, xpad);
  small_init_kernel<<<202, 256, 0, stream>>>(zb, cnt, sinA, cosA, alpha);

  LstmArgs a;
  a.xpad = xpad; a.wx0 = wx0; a.zero = zb;
  a.wh0 = wh0; a.wh1 = wh1; a.wi1 = wi1;
  a.h0 = h0; a.h1 = h1;
  a.b0f = b0f; a.b0b = b0b; a.b1f = b1f; a.b1b = b1b;
  a.counter = cnt;
  lstm_kernel<<<NWG, 256, 0, stream>>>(a);

  fc_kernel<<<TT, 256, 0, stream>>>(h1, xpad, wfc, fcb, sinA, cosA, pts);
  nerf_kernel<<<1, 64, 0, stream>>>(pts, (float*)d_out);
}

// Round 4
// 19905.396 us; speedup vs baseline: 2.0045x; 2.0045x over previous
//
#include <hip/hip_runtime.h>
#include <hip/hip_bf16.h>
#include <math.h>

// ---------------------------------------------------------------------------
// RGN model: T=700 B=32 H=800 EMB=32 EVO=21 A=60
// f32 in / f32 out; internal bf16 MFMA.
// Persistent biLSTM: weights stay L2-resident (no fences); only the h
// exchange goes through device-coherent (agent-scope) atomics to IF$.
// ---------------------------------------------------------------------------

typedef unsigned int u32;
typedef __bf16 bf16x8 __attribute__((ext_vector_type(8)));
typedef float  f32x4  __attribute__((ext_vector_type(4)));

#define TT 700
#define BT 32
#define HROW 1600
#define ASTRIDE 872        // LDS A stride (bf16 elems): 16B aligned
#define NWG 100

__device__ __forceinline__ f32x4 mfma16(bf16x8 a, bf16x8 b, f32x4 c) {
  return __builtin_amdgcn_mfma_f32_16x16x32_bf16(a, b, c, 0, 0, 0);
}
__device__ __forceinline__ float sigf(float x) { return 1.f / (1.f + __expf(-x)); }

#define ALOAD(p)    __hip_atomic_load((p), __ATOMIC_RELAXED, __HIP_MEMORY_SCOPE_AGENT)
#define ASTORE(p,v) __hip_atomic_store((p), (v), __ATOMIC_RELAXED, __HIP_MEMORY_SCOPE_AGENT)

// ---------------- pack / init kernels ----------------
__global__ void cvt_f32_bf16_kernel(const float* __restrict__ src,
                                    __bf16* __restrict__ dst, int n) {
  for (int i = blockIdx.x * 256 + threadIdx.x; i < n; i += gridDim.x * 256)
    dst[i] = (__bf16)src[i];
}

__global__ void pack_wx0_kernel(const float* Wih0f, const float* Wih0b, __bf16* wx0) {
  int idx = blockIdx.x * 256 + threadIdx.x;      // 2*3200*64 = 409600 exact
  if (idx >= 2 * 3200 * 64) return;
  int d = idx / (3200 * 64);
  int r = (idx / 64) % 3200;
  int k = idx % 64;
  const float* W = d ? Wih0b : Wih0f;
  wx0[idx] = (k < 53) ? (__bf16)W[(size_t)r * 53 + k] : (__bf16)0.f;
}

__global__ void pack_fc_kernel(const float* fcW, __bf16* wfc) {
  int idx = blockIdx.x * 256 + threadIdx.x;
  if (idx >= 64 * 1664) return;
  int a = idx / 1664, k = idx % 1664;
  __bf16 v = (__bf16)0.f;
  if (a < 60 && k < 1653) v = (__bf16)fcW[(size_t)a * 1653 + k];
  wfc[idx] = v;
}

__global__ void xpad_kernel(const int* primary, const float* evo,
                            const float* emb, __bf16* xpad) {
  int idx = blockIdx.x * 256 + threadIdx.x;   // 700*32*64 exact
  int t = idx >> 11;
  int b = (idx >> 6) & 31;
  int k = idx & 63;
  __bf16 v = (__bf16)0.f;
  if (k < 32)      v = (__bf16)emb[primary[t * 32 + b] * 32 + k];
  else if (k < 53) v = (__bf16)evo[((size_t)t * 32 + b) * 21 + (k - 32)];
  xpad[idx] = v;
}

__global__ void small_init_kernel(__bf16* zerobuf, u32* counter,
                                  float* sinA, float* cosA, const float* alpha) {
  int idx = blockIdx.x * 256 + threadIdx.x;
  if (idx < 32 * 1600) zerobuf[idx] = (__bf16)0.f;
  int j = idx - 32 * 1600;
  if (j >= 0 && j < 192) {
    if (j < 180) {
      float v = alpha[j];
      sinA[j] = sinf(v);
      cosA[j] = cosf(v);
    } else { sinA[j] = 0.f; cosA[j] = 0.f; }
  }
  if (j == 192) *counter = 0u;
}

// ---------------- persistent biLSTM ----------------
struct LstmArgs {
  const __bf16 *xpad, *wx0, *zero;
  const __bf16 *wh0, *wh1, *wi1;     // packed bf16: [dir][3200][800/800/1600]
  __bf16 *h0, *h1;
  const float *b0f, *b0b, *b1f, *b1b;
  u32* counter;
};

// Global barrier with NO cache invalidation: h traffic is device-coherent via
// agent-scope atomics (IF$ is the coherence point), so weights stay in L2.
__device__ __forceinline__ void gbar(u32* cnt, unsigned& gen) {
  asm volatile("s_waitcnt vmcnt(0)" ::: "memory");  // all h stores globally visible
  __syncthreads();
  ++gen;
  if (threadIdx.x == 0) {
    __hip_atomic_fetch_add(cnt, 1u, __ATOMIC_RELAXED, __HIP_MEMORY_SCOPE_AGENT);
    const unsigned tgt = gen * (unsigned)NWG;
    while (ALOAD(cnt) < tgt) __builtin_amdgcn_s_sleep(1);
  }
  __syncthreads();
}

template <int LAYER>
__device__ __forceinline__ void run_layer(
    const __bf16* __restrict__ Whh,   // (3200,800) bf16, dir-selected
    const __bf16* __restrict__ Wx,    // L0: wx0 dir (3200,64); L1: wi1 dir (3200,1600)
    const float*  __restrict__ bias,
    const __bf16* __restrict__ aux,   // L0: xpad [t][b][64]; L1: h0 [t][b][1600]
    const __bf16* __restrict__ hself, // own-layer h output (prev-step source)
    __bf16* __restrict__ hdst,
    const __bf16* __restrict__ zerobuf,
    u32* counter, unsigned& gen, int d, int u0,
    __bf16* u_lds, float* g_lds) {
  constexpr int NPASS = LAYER ? 3 : 1;

  const int tid  = threadIdx.x;
  const int wave = tid >> 6;
  const int lane = tid & 63;
  const int nidx = lane & 15;
  const int q    = lane >> 4;
  const int dcol = d * 800;
  const int row  = wave * 800 + u0 + nidx;          // gate row in [0,3200)
  const float bias_n = bias[row];
  const __bf16* whh_row = Whh + (size_t)row * 800 + q * 8;
  const __bf16* wx_row  = LAYER ? (Wx + (size_t)row * 1600 + q * 8)
                                : (Wx + (size_t)row * 64 + q * 8);
  const int bb = tid >> 3, g0 = tid & 7;
  const int up = tid & 7;                // unit-pair for nonlinearity (b = bb)
  float cA = 0.f, cB = 0.f;

#pragma unroll 1
  for (int s = 0; s < TT; ++s) {
    const int tt = d ? (TT - 1 - s) : s;
    const __bf16* hprev =
        (s == 0) ? zerobuf
                 : (hself + (size_t)(d ? tt + 1 : tt - 1) * (BT * HROW));
    f32x4 acc0 = {0.f, 0.f, 0.f, 0.f}, acc1 = {0.f, 0.f, 0.f, 0.f};

#pragma unroll
    for (int pass = 0; pass < NPASS; ++pass) {
      // ---- stage u chunk into LDS ----
      if (pass == 0) {
        // hprev: device-coherent dword loads (bypass stale-free path via IF$)
        for (int g = g0; g < 100; g += 8) {
          const int kk = g * 8;
          const u32* hp = (const u32*)(hprev + (size_t)bb * HROW + dcol + kk);
          u32 w0 = ALOAD(hp + 0);
          u32 w1 = ALOAD(hp + 1);
          u32 w2 = ALOAD(hp + 2);
          u32 w3 = ALOAD(hp + 3);
          u32* dst = (u32*)(u_lds + bb * ASTRIDE + kk);
          dst[0] = w0; dst[1] = w1; dst[2] = w2; dst[3] = w3;
        }
        if (LAYER == 0) {
          // x tail: groups 100..107, cacheable (read-only data)
          const int g = 100 + g0;
          const int kk = g * 8;
          bf16x8 v = *(const bf16x8*)(aux + ((size_t)tt * BT + bb) * 64 + (kk - 800));
          *(bf16x8*)(u_lds + bb * ASTRIDE + kk) = v;
        }
      } else {
        // L1 aux = h0 (stable this phase): cacheable vector loads
        for (int g = g0; g < 100; g += 8) {
          const int kk = g * 8;
          bf16x8 v = *(const bf16x8*)(aux + ((size_t)tt * BT + bb) * HROW +
                                      (pass - 1) * 800 + kk);
          *(bf16x8*)(u_lds + bb * ASTRIDE + kk) = v;
        }
      }
      __syncthreads();

      if (LAYER == 0) {
#pragma unroll
        for (int sl = 0; sl < 25; ++sl) {       // k in [0,800): Whh (L2-hot)
          bf16x8 bfr = *(const bf16x8*)(whh_row + sl * 32);
          bf16x8 a0 = *(const bf16x8*)(u_lds + nidx * ASTRIDE + sl * 32 + q * 8);
          bf16x8 a1 = *(const bf16x8*)(u_lds + (16 + nidx) * ASTRIDE + sl * 32 + q * 8);
          acc0 = mfma16(a0, bfr, acc0);
          acc1 = mfma16(a1, bfr, acc1);
        }
#pragma unroll
        for (int sl = 25; sl < 27; ++sl) {      // k in [800,864): packed x-part
          bf16x8 bfr = *(const bf16x8*)(wx_row + (sl - 25) * 32);
          bf16x8 a0 = *(const bf16x8*)(u_lds + nidx * ASTRIDE + sl * 32 + q * 8);
          bf16x8 a1 = *(const bf16x8*)(u_lds + (16 + nidx) * ASTRIDE + sl * 32 + q * 8);
          acc0 = mfma16(a0, bfr, acc0);
          acc1 = mfma16(a1, bfr, acc1);
        }
      } else {
        const __bf16* wr = (pass == 0) ? whh_row : (wx_row + (pass - 1) * 800);
#pragma unroll
        for (int sl = 0; sl < 25; ++sl) {
          bf16x8 bfr = *(const bf16x8*)(wr + sl * 32);
          bf16x8 a0 = *(const bf16x8*)(u_lds + nidx * ASTRIDE + sl * 32 + q * 8);
          bf16x8 a1 = *(const bf16x8*)(u_lds + (16 + nidx) * ASTRIDE + sl * 32 + q * 8);
          acc0 = mfma16(a0, bfr, acc0);
          acc1 = mfma16(a1, bfr, acc1);
        }
      }
      __syncthreads();
    }

    // ---- gate exchange (C layout: col=lane&15=unit, row=q*4+r=batch) ----
#pragma unroll
    for (int r = 0; r < 4; ++r) {
      g_lds[wave * 512 + (q * 4 + r) * 16 + nidx]      = acc0[r] + bias_n;
      g_lds[wave * 512 + (16 + q * 4 + r) * 16 + nidx] = acc1[r] + bias_n;
    }
    __syncthreads();

    // ---- nonlinearity: thread owns (b=bb, units u0+2*up, u0+2*up+1) ----
    {
      const int uA = 2 * up, uB = uA + 1;
      float iA = g_lds[0 * 512 + bb * 16 + uA], fA = g_lds[1 * 512 + bb * 16 + uA];
      float gA = g_lds[2 * 512 + bb * 16 + uA], oA = g_lds[3 * 512 + bb * 16 + uA];
      cA = sigf(fA) * cA + sigf(iA) * tanhf(gA);
      float hA = sigf(oA) * tanhf(cA);
      float iB = g_lds[0 * 512 + bb * 16 + uB], fB = g_lds[1 * 512 + bb * 16 + uB];
      float gB = g_lds[2 * 512 + bb * 16 + uB], oB = g_lds[3 * 512 + bb * 16 + uB];
      cB = sigf(fB) * cB + sigf(iB) * tanhf(gB);
      float hB = sigf(oB) * tanhf(cB);
      union { u32 u; __bf16 h2[2]; } pk;
      pk.h2[0] = (__bf16)hA;
      pk.h2[1] = (__bf16)hB;
      ASTORE((u32*)(hdst + ((size_t)tt * BT + bb) * HROW + dcol + u0 + uA), pk.u);
    }
    gbar(counter, gen);
  }
}

__global__ __launch_bounds__(256, 1) void lstm_kernel(LstmArgs A) {
  __shared__ __align__(16) __bf16 u_lds[32 * ASTRIDE];  // 55,808 B
  __shared__ float g_lds[4 * 32 * 16];                  // 8,192 B
  const int wg = blockIdx.x;
  const int d  = wg / 50;
  const int u0 = (wg % 50) * 16;
  unsigned gen = 0;
  run_layer<0>(A.wh0 + (size_t)d * 3200 * 800, A.wx0 + (size_t)d * 3200 * 64,
               d ? A.b0b : A.b0f, A.xpad, A.h0, A.h0, A.zero,
               A.counter, gen, d, u0, u_lds, g_lds);
  run_layer<1>(A.wh1 + (size_t)d * 3200 * 800, A.wi1 + (size_t)d * 3200 * 1600,
               d ? A.b1b : A.b1f, A.h0, A.h1, A.h1, A.zero,
               A.counter, gen, d, u0, u_lds, g_lds);
}

// ---------------- FC + softmax + dihedral -> points ----------------
__global__ __launch_bounds__(256) void fc_kernel(
    const __bf16* __restrict__ h1, const __bf16* __restrict__ xpad,
    const __bf16* __restrict__ wfc, const float* __restrict__ fcb,
    const float* __restrict__ sinA, const float* __restrict__ cosA,
    float* __restrict__ pts) {
  __shared__ float lg[32 * 64];
  const int t = blockIdx.x, tid = threadIdx.x;
  const int wave = tid >> 6, lane = tid & 63, nidx = lane & 15, q = lane >> 4;
  const int a_col = wave * 16 + nidx;
  const __bf16* wrow = wfc + (size_t)a_col * 1664 + q * 8;
  const __bf16* h1row = h1 + (size_t)t * BT * HROW;
  const __bf16* xrow  = xpad + (size_t)t * BT * 64;
  f32x4 acc0 = {0.f, 0.f, 0.f, 0.f}, acc1 = {0.f, 0.f, 0.f, 0.f};
#pragma unroll
  for (int sl = 0; sl < 52; ++sl) {
    const int k = sl * 32 + q * 8;
    bf16x8 a0, a1;
    if (sl < 50) {
      a0 = *(const bf16x8*)(h1row + (size_t)nidx * HROW + k);
      a1 = *(const bf16x8*)(h1row + (size_t)(16 + nidx) * HROW + k);
    } else {
      a0 = *(const bf16x8*)(xrow + nidx * 64 + (k - 1600));
      a1 = *(const bf16x8*)(xrow + (16 + nidx) * 64 + (k - 1600));
    }
    bf16x8 bfr = *(const bf16x8*)(wrow + sl * 32);
    acc0 = mfma16(a0, bfr, acc0);
    acc1 = mfma16(a1, bfr, acc1);
  }
  const float bn = (a_col < 60) ? fcb[a_col] : -1e30f;
#pragma unroll
  for (int r = 0; r < 4; ++r) {
    lg[(q * 4 + r) * 64 + a_col]      = acc0[r] + bn;
    lg[(16 + q * 4 + r) * 64 + a_col] = acc1[r] + bn;
  }
  __syncthreads();

  // softmax over 60 + dihedral; 8 threads per batch row
  const int b = tid >> 3, j = tid & 7;
  float v[8];
  float m = -1e30f;
#pragma unroll
  for (int k2 = 0; k2 < 8; ++k2) {
    v[k2] = lg[b * 64 + j + 8 * k2];
    m = fmaxf(m, v[k2]);
  }
  m = fmaxf(m, __shfl_xor(m, 1, 8));
  m = fmaxf(m, __shfl_xor(m, 2, 8));
  m = fmaxf(m, __shfl_xor(m, 4, 8));
  float s = 0.f;
#pragma unroll
  for (int k2 = 0; k2 < 8; ++k2) { v[k2] = __expf(v[k2] - m); s += v[k2]; }
  s += __shfl_xor(s, 1, 8);
  s += __shfl_xor(s, 2, 8);
  s += __shfl_xor(s, 4, 8);
  const float inv = 1.f / s;
  float ps[3] = {0.f, 0.f, 0.f}, pc[3] = {0.f, 0.f, 0.f};
#pragma unroll
  for (int k2 = 0; k2 < 8; ++k2) {
    const int a = j + 8 * k2;
    const float p = v[k2] * inv;
#pragma unroll
    for (int c = 0; c < 3; ++c) {
      ps[c] += p * sinA[a * 3 + c];
      pc[c] += p * cosA[a * 3 + c];
    }
  }
#pragma unroll
  for (int c = 0; c < 3; ++c) {
    ps[c] += __shfl_xor(ps[c], 1, 8);
    ps[c] += __shfl_xor(ps[c], 2, 8);
    ps[c] += __shfl_xor(ps[c], 4, 8);
    pc[c] += __shfl_xor(pc[c], 1, 8);
    pc[c] += __shfl_xor(pc[c], 2, 8);
    pc[c] += __shfl_xor(pc[c], 4, 8);
  }
  if (j == 0) {
    const float BL[3] = {145.801f, 152.326f, 132.868f};
    const float BA[3] = {2.124f, 1.941f, 2.028f};
#pragma unroll
    for (int c = 0; c < 3; ++c) {
      const float ang = 3.14159265358979323846f - BA[c];
      const float rct = BL[c] * cosf(ang), rst = BL[c] * sinf(ang);
      const float dih = atan2f(ps[c], pc[c]);
      float* o = pts + ((size_t)(3 * t + c) * BT + b) * 3;
      o[0] = rct;
      o[1] = cosf(dih) * rst;
      o[2] = sinf(dih) * rst;
    }
  }
}

// ---------------- sequential NeRF extension ----------------
__global__ void nerf_kernel(const float* __restrict__ pts, float* __restrict__ out) {
  const int b = threadIdx.x;
  if (b >= 32) return;
  float ax = -0.70710678f, ay = 1.22474487f, az = 0.f;
  float bx = -1.41421356f, by = 0.f, bz = 0.f;
  float cx = 0.f, cy = 0.f, cz = 0.f;
#pragma unroll 4
  for (int i = 0; i < 3 * TT; ++i) {
    const float* p = pts + ((size_t)i * BT + b) * 3;
    const float p0 = p[0], p1 = p[1], p2 = p[2];
    float ux = cx - bx, uy = cy - by, uz = cz - bz;
    const float ri = rsqrtf(ux * ux + uy * uy + uz * uz + 1e-12f);
    ux *= ri; uy *= ri; uz *= ri;
    const float wx = bx - ax, wy = by - ay, wz = bz - az;
    float nx = wy * uz - wz * uy, ny = wz * ux - wx * uz, nz = wx * uy - wy * ux;
    const float rn = rsqrtf(nx * nx + ny * ny + nz * nz + 1e-12f);
    nx *= rn; ny *= rn; nz *= rn;
    const float mx = ny * uz - nz * uy, my = nz * ux - nx * uz, mz = nx * uy - ny * ux;
    const float ox = cx + p0 * ux + p1 * mx + p2 * nx;
    const float oy = cy + p0 * uy + p1 * my + p2 * ny;
    const float oz = cz + p0 * uz + p1 * mz + p2 * nz;
    out[((size_t)i * BT + b) * 3 + 0] = ox;
    out[((size_t)i * BT + b) * 3 + 1] = oy;
    out[((size_t)i * BT + b) * 3 + 2] = oz;
    ax = bx; ay = by; az = bz;
    bx = cx; by = cy; bz = cz;
    cx = ox; cy = oy; cz = oz;
  }
}

// ---------------- launch ----------------
extern "C" void kernel_launch(void* const* d_in, const int* in_sizes, int n_in,
                              void* d_out, int out_size, void* d_ws, size_t ws_size,
                              hipStream_t stream) {
  (void)in_sizes; (void)n_in; (void)out_size;
  const int*   primary = (const int*)d_in[0];
  const float* evo     = (const float*)d_in[1];
  const float* emb     = (const float*)d_in[3];
  const float* Wih0f   = (const float*)d_in[4];
  const float* Whh0f   = (const float*)d_in[5];
  const float* b0f     = (const float*)d_in[6];
  const float* Wih0b   = (const float*)d_in[7];
  const float* Whh0b   = (const float*)d_in[8];
  const float* b0b     = (const float*)d_in[9];
  const float* Wih1f   = (const float*)d_in[10];
  const float* Whh1f   = (const float*)d_in[11];
  const float* b1f     = (const float*)d_in[12];
  const float* Wih1b   = (const float*)d_in[13];
  const float* Whh1b   = (const float*)d_in[14];
  const float* b1b     = (const float*)d_in[15];
  const float* fcW     = (const float*)d_in[16];
  const float* fcb     = (const float*)d_in[17];
  const float* alpha   = (const float*)d_in[18];

  char* ws = (char*)d_ws;
  size_t off = 0;
  auto take = [&](size_t n) -> void* {
    void* p = ws + off;
    off += (n + 511) & ~(size_t)511;
    return p;
  };
  __bf16* xpad = (__bf16*)take((size_t)TT * BT * 64 * 2);      // 2.87 MB
  __bf16* zb   = (__bf16*)take((size_t)BT * HROW * 2);         // 102 KB
  __bf16* wx0  = (__bf16*)take((size_t)2 * 3200 * 64 * 2);     // 819 KB
  __bf16* wfc  = (__bf16*)take((size_t)64 * 1664 * 2);         // 213 KB
  float*  sinA = (float*)take(192 * 4);
  float*  cosA = (float*)take(192 * 4);
  float*  pts  = (float*)take((size_t)3 * TT * BT * 3 * 4);    // 806 KB
  u32*    cnt  = (u32*)take(512);
  __bf16* wh0  = (__bf16*)take((size_t)2 * 3200 * 800 * 2);    // 10.24 MB
  __bf16* wh1  = (__bf16*)take((size_t)2 * 3200 * 800 * 2);    // 10.24 MB
  __bf16* wi1  = (__bf16*)take((size_t)2 * 3200 * 1600 * 2);   // 20.48 MB
  __bf16* h0   = (__bf16*)take((size_t)TT * BT * HROW * 2);    // 71.68 MB
  __bf16* h1   = (__bf16*)take((size_t)TT * BT * HROW * 2);    // 71.68 MB
  if (off > ws_size) return;  // failure signature: absmax == max|ref| == 233472

  const int NW = 3200 * 800;   // 2.56M elems per direction (Whh)
  const int NI = 3200 * 1600;  // 5.12M elems per direction (Wih1)
  cvt_f32_bf16_kernel<<<2048, 256, 0, stream>>>(Whh0f, wh0, NW);
  cvt_f32_bf16_kernel<<<2048, 256, 0, stream>>>(Whh0b, wh0 + NW, NW);
  cvt_f32_bf16_kernel<<<2048, 256, 0, stream>>>(Whh1f, wh1, NW);
  cvt_f32_bf16_kernel<<<2048, 256, 0, stream>>>(Whh1b, wh1 + NW, NW);
  cvt_f32_bf16_kernel<<<2048, 256, 0, stream>>>(Wih1f, wi1, NI);
  cvt_f32_bf16_kernel<<<2048, 256, 0, stream>>>(Wih1b, wi1 + NI, NI);
  pack_wx0_kernel<<<1600, 256, 0, stream>>>(Wih0f, Wih0b, wx0);
  pack_fc_kernel<<<(64 * 1664 + 255) / 256, 256, 0, stream>>>(fcW, wfc);
  xpad_kernel<<<(TT * BT * 64) / 256, 256, 0, stream>>>(primary, evo, emb, xpad);
  small_init_kernel<<<202, 256, 0, stream>>>(zb, cnt, sinA, cosA, alpha);

  LstmArgs a;
  a.xpad = xpad; a.wx0 = wx0; a.zero = zb;
  a.wh0 = wh0; a.wh1 = wh1; a.wi1 = wi1;
  a.h0 = h0; a.h1 = h1;
  a.b0f = b0f; a.b0b = b0b; a.b1f = b1f; a.b1b = b1b;
  a.counter = cnt;
  lstm_kernel<<<NWG, 256, 0, stream>>>(a);

  fc_kernel<<<TT, 256, 0, stream>>>(h1, xpad, wfc, fcb, sinA, cosA, pts);
  nerf_kernel<<<1, 64, 0, stream>>>(pts, (float*)d_out);
}